// Round 2
// baseline (174.331 us; speedup 1.0000x reference)
//
#include <hip/hip_runtime.h>
#include <hip/hip_bf16.h>
#include <stdint.h>

typedef unsigned int u32;

#define BATCH 64
#define ROOT 128
#define NLEAF 7
#define LHEAD 4
#define HDIM 128
#define NNODES 1024
#define OUTROWS 1025
#define NREL1 65          // NUM_REL + 1
#define MS_STRIDE 65      // dwords per LDS M row (64 bf16x2 + 1 pad -> 2-way alias, free)

// Precomputed u = M^T r_even, v = M^T r_odd per relation (fp32).
__device__ float g_U[NREL1 * HDIM];
__device__ float g_V[NREL1 * HDIM];

static __device__ __forceinline__ float bf16_lo(u32 u) {
    return __builtin_bit_cast(float, u << 16);
}
static __device__ __forceinline__ float bf16_hi(u32 u) {
    return __builtin_bit_cast(float, u & 0xffff0000u);
}
// round-to-nearest-even fp32 -> bf16 (returned in low 16 bits)
static __device__ __forceinline__ u32 rne_bf16(float f) {
    u32 u = __builtin_bit_cast(u32, f);
    return (u + 0x7fffu + ((u >> 16) & 1u)) >> 16;
}
static __device__ __forceinline__ u32 pack_bf16(float a, float b) {
    return rne_bf16(a) | (rne_bf16(b) << 16);
}

// ---------------------------------------------------------------------------
// Kernel A: U[rel][j] = sum_i M[i][j]*r[2i],  V[rel][j] = sum_i M[i][j]*r[2i+1]
// grid = 65, block = 128  (fp32 throughout)
// ---------------------------------------------------------------------------
__global__ void uv_kernel(const float* __restrict__ rel_mat,
                          const float* __restrict__ rel_emb) {
    int rel = blockIdx.x;
    int j = threadIdx.x;
    const float* M = rel_mat + (size_t)rel * HDIM * HDIM;
    const float* r = rel_emb + (size_t)rel * 2 * HDIM;
    float u = 0.f, v = 0.f;
    for (int i = 0; i < HDIM; ++i) {
        float m = M[i * HDIM + j];              // coalesced across j
        u += r[2 * i] * m;
        v += r[2 * i + 1] * m;
    }
    g_U[rel * HDIM + j] = u;
    g_V[rel * HDIM + j] = v;
}

// ---------------------------------------------------------------------------
// Kernel B: out[b][0][:] = graph_token; out[b][1+n][:] = atom_emb[tok[b][n]]
// for n in 0..127 (root rows get no scatter-adds). float4 copies.
// ---------------------------------------------------------------------------
__global__ void base_kernel(const int* __restrict__ tok,
                            const float4* __restrict__ atom4,
                            const float4* __restrict__ gtok4,
                            float4* __restrict__ out4) {
    const int per_b = 129 * (HDIM / 4);         // float4s per batch segment
    int p = blockIdx.x * 256 + threadIdx.x;
    if (p >= BATCH * per_b) return;
    int b = p / per_b;
    int rem = p - b * per_b;
    int n = rem >> 5;                           // 32 float4 per row
    int h4 = rem & 31;
    float4 v;
    if (n == 0) v = gtok4[h4];
    else        v = atom4[(size_t)tok[b * NNODES + (n - 1)] * 32 + h4];
    out4[(size_t)b * OUTROWS * 32 + rem] = v;
}

// ---------------------------------------------------------------------------
// Kernel C: one block per triple (b, rn). 256 threads.
//   he[l] = atom[head_tok], te[t] = atom[tail_tok]
//   a[t] = U[rel]·te[t]; bb[l] = V[rel]·he[l]
//   alpha = softmax_l(leaky(a+b)); Mh[l] = M·he[l]
//   out[b][129+rn*7+t][:] = te[t] + sum_l alpha[t][l]*Mh[l]
// M staged fp32->bf16(RNE) in LDS; all accumulation fp32.
// ---------------------------------------------------------------------------
__global__ __launch_bounds__(256) void triple_kernel(
    const int* __restrict__ tok,
    const int* __restrict__ leaf_rel,
    const float* __restrict__ rel_mat,
    const float* __restrict__ atom,
    float* __restrict__ out)
{
    int rn = blockIdx.x;
    int b  = blockIdx.y;
    int tid = threadIdx.x;

    __shared__ u32 Ms[HDIM * MS_STRIDE];                 // 33280 B, padded rows
    __shared__ __align__(16) float heT[HDIM * LHEAD];    // [j][l]
    __shared__ float te_s[NLEAF * HDIM];                 // [t][j]
    __shared__ __align__(16) float Mh_s[HDIM * LHEAD];   // [i][l]
    __shared__ float a_s[NLEAF], b_s[LHEAD];
    __shared__ float alpha_s[NLEAF * LHEAD];
    __shared__ int s_tok[LHEAD + NLEAF];

    // tokens for this triple
    if (tid < LHEAD) {
        int hp = rn + tid; if (hp > ROOT - 1) hp = ROOT - 1;   // torch clip
        s_tok[tid] = tok[b * NNODES + hp];
    } else if (tid < LHEAD + NLEAF) {
        int t = tid - LHEAD;
        s_tok[tid] = tok[b * NNODES + ROOT + rn * NLEAF + t];
    }
    int rel = leaf_rel[b * ROOT + rn];
    __syncthreads();

    // stage M into LDS as packed bf16x2 (global float4 loads, coalesced)
    const float4* Mg4 = (const float4*)(rel_mat + (size_t)rel * HDIM * HDIM);
    #pragma unroll
    for (int it = 0; it < 16; ++it) {
        int d4 = it * 256 + tid;          // 4096 float4 total; 32 per row
        float4 w = Mg4[d4];
        int i = d4 >> 5;
        int k = (d4 & 31) * 2;            // dword pair within padded row
        u32* dst = &Ms[i * MS_STRIDE + k];
        dst[0] = pack_bf16(w.x, w.y);
        dst[1] = pack_bf16(w.z, w.w);
    }

    // he (transposed [j][l]) and te ([t][j]) as fp32
    for (int e = tid; e < LHEAD * HDIM; e += 256) {
        int l = e >> 7, j = e & 127;
        heT[j * LHEAD + l] = atom[(size_t)s_tok[l] * HDIM + j];
    }
    for (int e = tid; e < NLEAF * HDIM; e += 256) {
        int t = e >> 7, j = e & 127;
        (void)t;
        te_s[e] = atom[(size_t)s_tok[LHEAD + (e >> 7)] * HDIM + j];
    }
    __syncthreads();

    // a/b dot products: 11 length-128 dots, round-robin across 4 waves
    int wave = tid >> 6, lane = tid & 63;
    const float* u = &g_U[rel * HDIM];
    const float* v = &g_V[rel * HDIM];
    for (int d = wave; d < NLEAF + LHEAD; d += 4) {
        float p;
        if (d < NLEAF) {
            p = u[lane]      * te_s[d * HDIM + lane]
              + u[lane + 64] * te_s[d * HDIM + lane + 64];
        } else {
            int l = d - NLEAF;
            p = v[lane]      * heT[lane * LHEAD + l]
              + v[lane + 64] * heT[(lane + 64) * LHEAD + l];
        }
        #pragma unroll
        for (int m = 32; m > 0; m >>= 1) p += __shfl_xor(p, m, 64);
        if (lane == 0) {
            if (d < NLEAF) a_s[d] = p; else b_s[d - NLEAF] = p;
        }
    }
    __syncthreads();

    // softmax over 4 heads per tail (leaky_relu slope 0.01)
    if (tid < NLEAF) {
        float sc[LHEAD];
        float mx = -1e30f;
        #pragma unroll
        for (int l = 0; l < LHEAD; ++l) {
            float x = a_s[tid] + b_s[l];
            x = (x >= 0.f) ? x : 0.01f * x;
            sc[l] = x; mx = fmaxf(mx, x);
        }
        float sum = 0.f;
        #pragma unroll
        for (int l = 0; l < LHEAD; ++l) { sc[l] = __expf(sc[l] - mx); sum += sc[l]; }
        float inv = 1.f / sum;
        #pragma unroll
        for (int l = 0; l < LHEAD; ++l) alpha_s[tid * LHEAD + l] = sc[l] * inv;
    }

    // Mh[l][i] = sum_j M[i][j] he[l][j] — lane owns row i, half of j;
    // M row read as bf16x2 dwords (2-way bank alias = free); heT reads are
    // wave-uniform broadcasts (all lanes of a wave share k).
    int i = tid & 127, jhalf = tid >> 7;
    float mh0 = 0.f, mh1 = 0.f, mh2 = 0.f, mh3 = 0.f;
    int kbase = jhalf * 32;
    #pragma unroll
    for (int q = 0; q < 32; ++q) {
        int k = kbase + q;
        u32 mw = Ms[i * MS_STRIDE + k];
        float m0 = bf16_lo(mw), m1 = bf16_hi(mw);
        const float* h = &heT[(2 * k) * LHEAD];
        float4 h0 = *(const float4*)h;
        float4 h1 = *(const float4*)(h + LHEAD);
        mh0 += m0 * h0.x + m1 * h1.x;
        mh1 += m0 * h0.y + m1 * h1.y;
        mh2 += m0 * h0.z + m1 * h1.z;
        mh3 += m0 * h0.w + m1 * h1.w;
    }
    if (jhalf == 0) {
        Mh_s[i * LHEAD + 0] = mh0; Mh_s[i * LHEAD + 1] = mh1;
        Mh_s[i * LHEAD + 2] = mh2; Mh_s[i * LHEAD + 3] = mh3;
    }
    __syncthreads();
    if (jhalf == 1) {
        Mh_s[i * LHEAD + 0] += mh0; Mh_s[i * LHEAD + 1] += mh1;
        Mh_s[i * LHEAD + 2] += mh2; Mh_s[i * LHEAD + 3] += mh3;
    }
    __syncthreads();

    // leaf outputs: te + alpha·Mh, fp32 coalesced store
    size_t obase = (size_t)b * OUTROWS * HDIM + (size_t)(1 + ROOT + rn * NLEAF) * HDIM;
    for (int e = tid; e < NLEAF * HDIM; e += 256) {
        int t = e >> 7, j = e & 127;
        const float* mh = &Mh_s[j * LHEAD];
        const float* al = &alpha_s[t * LHEAD];
        out[obase + e] = te_s[e] + al[0]*mh[0] + al[1]*mh[1] + al[2]*mh[2] + al[3]*mh[3];
    }
}

// ---------------------------------------------------------------------------
extern "C" void kernel_launch(void* const* d_in, const int* in_sizes, int n_in,
                              void* d_out, int out_size, void* d_ws, size_t ws_size,
                              hipStream_t stream) {
    (void)in_sizes; (void)n_in; (void)out_size; (void)d_ws; (void)ws_size;
    const int* tok       = (const int*)d_in[0];     // [B,1024,1] int32
    const int* leaf_rel  = (const int*)d_in[1];     // [B,128]    int32
    // d_in[2] = head_lengths: unused by the reference body
    const float* atom    = (const float*)d_in[3];   // [30000,128] fp32
    const float* rel_mat = (const float*)d_in[4];   // [65,128*128] fp32
    const float* rel_emb = (const float*)d_in[5];   // [65,256] fp32
    const float* gtok    = (const float*)d_in[6];   // [1,128] fp32
    float* out = (float*)d_out;                     // [64,1025,128] fp32

    uv_kernel<<<NREL1, HDIM, 0, stream>>>(rel_mat, rel_emb);

    const int base_total = BATCH * 129 * (HDIM / 4);
    base_kernel<<<(base_total + 255) / 256, 256, 0, stream>>>(
        tok, (const float4*)atom, (const float4*)gtok, (float4*)out);

    dim3 grid(ROOT, BATCH);
    triple_kernel<<<grid, 256, 0, stream>>>(tok, leaf_rel, rel_mat, atom, out);
}

// Round 3
// 143.782 us; speedup vs baseline: 1.2125x; 1.2125x over previous
//
#include <hip/hip_runtime.h>
#include <hip/hip_bf16.h>
#include <stdint.h>

typedef unsigned int u32;

#define BATCH 64
#define ROOT 128
#define NLEAF 7
#define LHEAD 4
#define HDIM 128
#define NNODES 1024
#define OUTROWS 1025
#define NREL1 65          // NUM_REL + 1

// Precomputed per-relation data (written by prep_kernel every launch — idempotent):
//   g_U = M^T r_even, g_V = M^T r_odd (fp32)
//   g_Mpacked = M rounded to bf16, 2 values per dword (2.13 MB -> L2-resident per XCD)
__device__ float g_U[NREL1 * HDIM];
__device__ float g_V[NREL1 * HDIM];
__device__ u32   g_Mpacked[NREL1 * HDIM * HDIM / 2];

static __device__ __forceinline__ float bf16_lo(u32 u) {
    return __builtin_bit_cast(float, u << 16);
}
static __device__ __forceinline__ float bf16_hi(u32 u) {
    return __builtin_bit_cast(float, u & 0xffff0000u);
}
// round-to-nearest-even fp32 -> bf16 (low 16 bits)
static __device__ __forceinline__ u32 rne_bf16(float f) {
    u32 u = __builtin_bit_cast(u32, f);
    return (u + 0x7fffu + ((u >> 16) & 1u)) >> 16;
}
static __device__ __forceinline__ u32 pack_bf16(float a, float b) {
    return rne_bf16(a) | (rne_bf16(b) << 16);
}

// ---------------------------------------------------------------------------
// prep_kernel: grid (65, 5), block 256.
//  blockIdx.y < 4 : pack one quarter of M[rel] fp32 -> bf16x2 into g_Mpacked
//  blockIdx.y == 4: U[rel][j] = sum_i M[i][j] r[2i]; V likewise with r[2i+1]
// ---------------------------------------------------------------------------
__global__ void prep_kernel(const float* __restrict__ rel_mat,
                            const float* __restrict__ rel_emb) {
    int rel = blockIdx.x;
    int part = blockIdx.y;
    const float* M = rel_mat + (size_t)rel * HDIM * HDIM;

    if (part < 4) {
        const float2* M2 = (const float2*)M;
        u32* dst = &g_Mpacked[(size_t)rel * (HDIM * HDIM / 2)];
        #pragma unroll
        for (int q = 0; q < 8; ++q) {
            int d = part * 2048 + q * 256 + threadIdx.x;   // 8192 packed dwords/rel
            float2 w = M2[d];
            dst[d] = pack_bf16(w.x, w.y);
        }
    } else {
        int j = threadIdx.x & 127, half = threadIdx.x >> 7;
        const float* r = rel_emb + (size_t)rel * 2 * HDIM;
        float u = 0.f, v = 0.f;
        int i0 = half * 64;
        for (int i = i0; i < i0 + 64; ++i) {
            float m = M[i * HDIM + j];            // coalesced across j
            u += r[2 * i] * m;
            v += r[2 * i + 1] * m;
        }
        __shared__ float us[HDIM], vs[HDIM];
        if (half == 1) { us[j] = u; vs[j] = v; }
        __syncthreads();
        if (half == 0) {
            g_U[rel * HDIM + j] = u + us[j];
            g_V[rel * HDIM + j] = v + vs[j];
        }
    }
}

// ---------------------------------------------------------------------------
// triple_kernel: one block per (rn, b). 256 threads. ~8 KB LDS.
//   root row + graph token writes folded in (base_kernel eliminated).
//   M read directly global(bf16x2, L2-hot) -> registers; no LDS staging.
// ---------------------------------------------------------------------------
__global__ __launch_bounds__(256) void triple_kernel(
    const int* __restrict__ tok,
    const int* __restrict__ leaf_rel,
    const float* __restrict__ atom,
    const float* __restrict__ gtok,
    float* __restrict__ out)
{
    int rn = blockIdx.x;
    int b  = blockIdx.y;
    int tid = threadIdx.x;

    __shared__ __align__(16) float heT[HDIM * LHEAD];    // [j][l]
    __shared__ float te_s[NLEAF * HDIM];                 // [t][j]
    __shared__ __align__(16) float Mh_s[HDIM * LHEAD];   // [i][l]
    __shared__ float a_s[NLEAF], b_s[LHEAD];
    __shared__ float alpha_s[NLEAF * LHEAD];
    __shared__ int s_tok[LHEAD + NLEAF];

    int rel = leaf_rel[b * ROOT + rn];

    // ---- issue M loads early (registers; independent of all LDS phases) ----
    int i = tid & 127, jhalf = tid >> 7;
    const uint4* Mp = (const uint4*)(&g_Mpacked[((size_t)rel << 13) + i * 64 + jhalf * 32]);
    uint4 mw[8];
    #pragma unroll
    for (int q = 0; q < 8; ++q) mw[q] = Mp[q];

    // ---- tokens ----
    if (tid < LHEAD) {
        int hp = rn + tid; if (hp > ROOT - 1) hp = ROOT - 1;   // torch clip
        s_tok[tid] = tok[b * NNODES + hp];
    } else if (tid < LHEAD + NLEAF) {
        s_tok[tid] = tok[b * NNODES + ROOT + rn * NLEAF + (tid - LHEAD)];
    }
    __syncthreads();

    // ---- gather he (transposed [j][l]) and te ([t][j]) ----
    #pragma unroll
    for (int e = tid; e < LHEAD * HDIM; e += 256) {
        int l = e >> 7, j = e & 127;
        heT[j * LHEAD + l] = atom[(size_t)s_tok[l] * HDIM + j];
    }
    #pragma unroll
    for (int e = tid; e < NLEAF * HDIM; e += 256) {
        int j = e & 127;
        te_s[e] = atom[(size_t)s_tok[LHEAD + (e >> 7)] * HDIM + j];
    }
    __syncthreads();

    // ---- 11 length-128 dots, round-robin across 4 waves ----
    int wave = tid >> 6, lane = tid & 63;
    const float* u = &g_U[rel * HDIM];
    const float* v = &g_V[rel * HDIM];
    for (int d = wave; d < NLEAF + LHEAD; d += 4) {
        float p;
        if (d < NLEAF) {
            p = u[lane]      * te_s[d * HDIM + lane]
              + u[lane + 64] * te_s[d * HDIM + lane + 64];
        } else {
            const float* he = atom + (size_t)s_tok[d - NLEAF] * HDIM;  // coalesced, L2-hot
            p = v[lane] * he[lane] + v[lane + 64] * he[lane + 64];
        }
        #pragma unroll
        for (int m = 32; m > 0; m >>= 1) p += __shfl_xor(p, m, 64);
        if (lane == 0) {
            if (d < NLEAF) a_s[d] = p; else b_s[d - NLEAF] = p;
        }
    }
    __syncthreads();

    // ---- softmax over 4 heads per tail (leaky_relu slope 0.01) ----
    if (tid < NLEAF) {
        float sc[LHEAD];
        float mx = -1e30f;
        #pragma unroll
        for (int l = 0; l < LHEAD; ++l) {
            float x = a_s[tid] + b_s[l];
            x = (x >= 0.f) ? x : 0.01f * x;
            sc[l] = x; mx = fmaxf(mx, x);
        }
        float sum = 0.f;
        #pragma unroll
        for (int l = 0; l < LHEAD; ++l) { sc[l] = __expf(sc[l] - mx); sum += sc[l]; }
        float inv = 1.f / sum;
        #pragma unroll
        for (int l = 0; l < LHEAD; ++l) alpha_s[tid * LHEAD + l] = sc[l] * inv;
    }

    // ---- Mh[l][i] = sum_j M[i][j] he[l][j]; lane owns row i, half of j ----
    // heT reads are wave-uniform b128 broadcasts (k uniform within a wave).
    float mh0 = 0.f, mh1 = 0.f, mh2 = 0.f, mh3 = 0.f;
    #pragma unroll
    for (int q = 0; q < 8; ++q) {
        int jbase = jhalf * 64 + q * 8;                  // 8 bf16 j-values this uint4
        const float* h = &heT[jbase * LHEAD];
        u32 w0 = mw[q].x, w1 = mw[q].y, w2 = mw[q].z, w3 = mw[q].w;
        float4 h0 = *(const float4*)(h + 0);
        float4 h1 = *(const float4*)(h + 4);
        float4 h2 = *(const float4*)(h + 8);
        float4 h3 = *(const float4*)(h + 12);
        float4 h4 = *(const float4*)(h + 16);
        float4 h5 = *(const float4*)(h + 20);
        float4 h6 = *(const float4*)(h + 24);
        float4 h7 = *(const float4*)(h + 28);
        float m0 = bf16_lo(w0), m1 = bf16_hi(w0);
        float m2 = bf16_lo(w1), m3 = bf16_hi(w1);
        float m4 = bf16_lo(w2), m5 = bf16_hi(w2);
        float m6 = bf16_lo(w3), m7 = bf16_hi(w3);
        mh0 += m0*h0.x + m1*h1.x + m2*h2.x + m3*h3.x + m4*h4.x + m5*h5.x + m6*h6.x + m7*h7.x;
        mh1 += m0*h0.y + m1*h1.y + m2*h2.y + m3*h3.y + m4*h4.y + m5*h5.y + m6*h6.y + m7*h7.y;
        mh2 += m0*h0.z + m1*h1.z + m2*h2.z + m3*h3.z + m4*h4.z + m5*h5.z + m6*h6.z + m7*h7.z;
        mh3 += m0*h0.w + m1*h1.w + m2*h2.w + m3*h3.w + m4*h4.w + m5*h5.w + m6*h6.w + m7*h7.w;
    }
    if (jhalf == 0) {
        Mh_s[i * LHEAD + 0] = mh0; Mh_s[i * LHEAD + 1] = mh1;
        Mh_s[i * LHEAD + 2] = mh2; Mh_s[i * LHEAD + 3] = mh3;
    }
    __syncthreads();
    if (jhalf == 1) {
        Mh_s[i * LHEAD + 0] += mh0; Mh_s[i * LHEAD + 1] += mh1;
        Mh_s[i * LHEAD + 2] += mh2; Mh_s[i * LHEAD + 3] += mh3;
    }

    // ---- root row + graph token (absorbs old base_kernel) ----
    size_t bbase = (size_t)b * OUTROWS * HDIM;
    if (tid < HDIM) {
        out[bbase + (size_t)(1 + rn) * HDIM + tid] = atom[(size_t)s_tok[0] * HDIM + tid];
        if (rn == 0) out[bbase + tid] = gtok[tid];
    }
    __syncthreads();

    // ---- leaf outputs: te + alpha·Mh ----
    size_t obase = bbase + (size_t)(1 + ROOT + rn * NLEAF) * HDIM;
    #pragma unroll
    for (int e = tid; e < NLEAF * HDIM; e += 256) {
        int t = e >> 7, j = e & 127;
        const float4 mh = *(const float4*)&Mh_s[j * LHEAD];    // contiguous 16B/lane
        const float* al = &alpha_s[t * LHEAD];                 // wave-uniform broadcast
        out[obase + e] = te_s[e] + al[0]*mh.x + al[1]*mh.y + al[2]*mh.z + al[3]*mh.w;
    }
}

// ---------------------------------------------------------------------------
extern "C" void kernel_launch(void* const* d_in, const int* in_sizes, int n_in,
                              void* d_out, int out_size, void* d_ws, size_t ws_size,
                              hipStream_t stream) {
    (void)in_sizes; (void)n_in; (void)out_size; (void)d_ws; (void)ws_size;
    const int* tok       = (const int*)d_in[0];     // [B,1024,1] int32
    const int* leaf_rel  = (const int*)d_in[1];     // [B,128]    int32
    // d_in[2] = head_lengths: unused by the reference body
    const float* atom    = (const float*)d_in[3];   // [30000,128] fp32
    const float* rel_mat = (const float*)d_in[4];   // [65,128*128] fp32
    const float* rel_emb = (const float*)d_in[5];   // [65,256] fp32
    const float* gtok    = (const float*)d_in[6];   // [1,128] fp32
    float* out = (float*)d_out;                     // [64,1025,128] fp32

    dim3 pgrid(NREL1, 5);
    prep_kernel<<<pgrid, 256, 0, stream>>>(rel_mat, rel_emb);

    dim3 grid(ROOT, BATCH);
    triple_kernel<<<grid, 256, 0, stream>>>(tok, leaf_rel, atom, gtok, out);
}